// Round 3
// baseline (569.400 us; speedup 1.0000x reference)
//
#include <hip/hip_runtime.h>

typedef __bf16 bf16_t;
typedef __bf16 bf16x8 __attribute__((ext_vector_type(8)));
typedef float  f32x4  __attribute__((ext_vector_type(4)));

#define D_FEAT 512

// ---------------- convert x (f32) -> padded bf16 ----------------
__global__ void cvt_x_k(const float* __restrict__ x, bf16_t* __restrict__ xb,
                        int total, int valid) {
  int idx = (blockIdx.x * 256 + threadIdx.x) * 8;
  if (idx >= total) return;
  bf16x8 o;
  if (idx < valid) {
    const float4* p = (const float4*)(x + idx);
    float4 a = p[0], b = p[1];
    o[0] = (bf16_t)a.x; o[1] = (bf16_t)a.y; o[2] = (bf16_t)a.z; o[3] = (bf16_t)a.w;
    o[4] = (bf16_t)b.x; o[5] = (bf16_t)b.y; o[6] = (bf16_t)b.z; o[7] = (bf16_t)b.w;
  } else {
#pragma unroll
    for (int i = 0; i < 8; ++i) o[i] = (bf16_t)0.f;
  }
  *(bf16x8*)(xb + idx) = o;
}

// ------------- build combined weight WB[n][k] (bf16, [512][1024]) -------------
__global__ void cvt_w_k(const float* __restrict__ Wl, const float* __restrict__ Wr,
                        bf16_t* __restrict__ WB) {
  int idx = (blockIdx.x * 256 + threadIdx.x) * 8;  // into [512][1024]
  int n = idx >> 10, k = idx & 1023;
  const float* s = (k < 512) ? (Wl + n * 512 + k) : (Wr + n * 512 + k - 512);
  const float4* p = (const float4*)s;
  float4 a = p[0], b = p[1];
  bf16x8 o;
  o[0] = (bf16_t)a.x; o[1] = (bf16_t)a.y; o[2] = (bf16_t)a.z; o[3] = (bf16_t)a.w;
  o[4] = (bf16_t)b.x; o[5] = (bf16_t)b.y; o[6] = (bf16_t)b.z; o[7] = (bf16_t)b.w;
  *(bf16x8*)(WB + idx) = o;
}

// ---------------- CSR build ----------------
__global__ void deg_k(const int* __restrict__ dst, int* __restrict__ deg, int E) {
  int e = blockIdx.x * 256 + threadIdx.x;
  if (e < E) atomicAdd(&deg[dst[e]], 1);
}

__global__ void scan_part_k(const int* __restrict__ deg, int* __restrict__ partial, int N) {
  __shared__ int sd[512];
  int tid = threadIdx.x;
  int i = blockIdx.x * 512 + tid;
  sd[tid] = (i < N) ? deg[i] : 0;
  __syncthreads();
  for (int s = 256; s > 0; s >>= 1) {
    if (tid < s) sd[tid] += sd[tid + s];
    __syncthreads();
  }
  if (tid == 0) partial[blockIdx.x] = sd[0];
}

__global__ void scan_off_k(int* __restrict__ partial, int nb, int* __restrict__ rowS, int N) {
  if (threadIdx.x == 0 && blockIdx.x == 0) {
    int run = 0;
    for (int b = 0; b < nb; ++b) { int v = partial[b]; partial[b] = run; run += v; }
    rowS[N] = run;
  }
}

__global__ void scan_blk_k(const int* __restrict__ deg, const int* __restrict__ partial,
                           int* __restrict__ rowS, int* __restrict__ cursor, int N) {
  __shared__ int sd[512];
  int tid = threadIdx.x;
  int i = blockIdx.x * 512 + tid;
  int v = (i < N) ? deg[i] : 0;
  sd[tid] = v;
  __syncthreads();
  for (int offd = 1; offd < 512; offd <<= 1) {
    int t = (tid >= offd) ? sd[tid - offd] : 0;
    __syncthreads();
    sd[tid] += t;
    __syncthreads();
  }
  int excl = sd[tid] - v + partial[blockIdx.x];
  if (i < N) { rowS[i] = excl; cursor[i] = excl; }
}

__global__ void scat_k(const int* __restrict__ src, const int* __restrict__ dst,
                       int* __restrict__ cursor, int* __restrict__ col, int E) {
  int e = blockIdx.x * 256 + threadIdx.x;
  if (e < E) {
    int d = dst[e];
    int p = atomicAdd(&cursor[d], 1);
    col[p] = src[e];
  }
}

// ---------------- mean aggregation: out[i] = mean_{j in N(i)} X[col[j]] ----------------
__global__ __launch_bounds__(256) void agg_k(const bf16_t* __restrict__ X,
                                             const int* __restrict__ rs,
                                             const int* __restrict__ col,
                                             bf16_t* __restrict__ out,
                                             int N, int NPAD) {
  const int lane = threadIdx.x & 63;
  const int node = blockIdx.x * 4 + (threadIdx.x >> 6);
  if (node >= NPAD) return;
  const size_t obase = (size_t)node * D_FEAT + lane * 8;
  bf16x8 o;
  if (node >= N) {
#pragma unroll
    for (int i = 0; i < 8; ++i) o[i] = (bf16_t)0.f;
    *(bf16x8*)(out + obase) = o;
    return;
  }
  const int s = rs[node], e = rs[node + 1];
  const int loff = lane * 8;
  float acc[8] = {0.f, 0.f, 0.f, 0.f, 0.f, 0.f, 0.f, 0.f};
  int j = s;
  for (; j + 8 <= e; j += 8) {
    int c0 = col[j + 0], c1 = col[j + 1], c2 = col[j + 2], c3 = col[j + 3];
    int c4 = col[j + 4], c5 = col[j + 5], c6 = col[j + 6], c7 = col[j + 7];
    bf16x8 v0 = *(const bf16x8*)(X + (size_t)c0 * D_FEAT + loff);
    bf16x8 v1 = *(const bf16x8*)(X + (size_t)c1 * D_FEAT + loff);
    bf16x8 v2 = *(const bf16x8*)(X + (size_t)c2 * D_FEAT + loff);
    bf16x8 v3 = *(const bf16x8*)(X + (size_t)c3 * D_FEAT + loff);
    bf16x8 v4 = *(const bf16x8*)(X + (size_t)c4 * D_FEAT + loff);
    bf16x8 v5 = *(const bf16x8*)(X + (size_t)c5 * D_FEAT + loff);
    bf16x8 v6 = *(const bf16x8*)(X + (size_t)c6 * D_FEAT + loff);
    bf16x8 v7 = *(const bf16x8*)(X + (size_t)c7 * D_FEAT + loff);
#pragma unroll
    for (int i = 0; i < 8; ++i) {
      float s01 = (float)v0[i] + (float)v1[i];
      float s23 = (float)v2[i] + (float)v3[i];
      float s45 = (float)v4[i] + (float)v5[i];
      float s67 = (float)v6[i] + (float)v7[i];
      acc[i] += (s01 + s23) + (s45 + s67);
    }
  }
  for (; j + 2 <= e; j += 2) {
    int c0 = col[j + 0], c1 = col[j + 1];
    bf16x8 v0 = *(const bf16x8*)(X + (size_t)c0 * D_FEAT + loff);
    bf16x8 v1 = *(const bf16x8*)(X + (size_t)c1 * D_FEAT + loff);
#pragma unroll
    for (int i = 0; i < 8; ++i) acc[i] += (float)v0[i] + (float)v1[i];
  }
  for (; j < e; ++j) {
    int c0 = col[j];
    bf16x8 v0 = *(const bf16x8*)(X + (size_t)c0 * D_FEAT + loff);
#pragma unroll
    for (int i = 0; i < 8; ++i) acc[i] += (float)v0[i];
  }
  float sc = (e > s) ? 1.0f / (float)(e - s) : 0.f;
#pragma unroll
  for (int i = 0; i < 8; ++i) o[i] = (bf16_t)(acc[i] * sc);
  *(bf16x8*)(out + obase) = o;
}

// ---------------- fused GEMM: out[m][n] = sum_k [A0|A1][m][k] * WB[n][k] + bias[n] ----------------
// 128x128 tile, BK=32, 4 waves (2x2), 16x16x32 bf16 MFMA, double-buffered LDS.
// Swizzle: LDS[row][slot] holds global k-chunk (slot ^ ((row>>1)&3)); involution applied
// on the global SOURCE address at stage time (LDS dest linear, per guide §5 rule 21) and
// on the ds_read slot. Decorrelates bank-group from row parity -> conflict-free b128 reads.
__device__ __forceinline__ void gload_lds16(const void* g, void* l) {
  __builtin_amdgcn_global_load_lds(
      (const __attribute__((address_space(1))) unsigned int*)g,
      (__attribute__((address_space(3))) unsigned int*)l,
      16, 0, 0);
}

template <bool RELU, typename OT>
__global__ __launch_bounds__(256) void gemm_k(
    const bf16_t* __restrict__ A0,   // K 0..511   (mean features)
    const bf16_t* __restrict__ A1,   // K 512..1023 (self features)
    const bf16_t* __restrict__ WB,   // [512][1024]
    const float* __restrict__ bias,  // [512]
    OT* __restrict__ out, int M) {
  __shared__ __align__(16) unsigned short smem[2 * 8192];  // per buf: A 4096 + B 4096 ushorts

  const int tid = threadIdx.x;
  const int lane = tid & 63;
  const int wave = tid >> 6;
  const int wr = wave >> 1, wc = wave & 1;
  const int m0 = blockIdx.y * 128;
  const int n0 = blockIdx.x * 128;

  f32x4 acc[4][4];
#pragma unroll
  for (int m = 0; m < 4; ++m)
#pragma unroll
    for (int n = 0; n < 4; ++n) acc[m][n] = (f32x4){0.f, 0.f, 0.f, 0.f};

  // ---- lane-constant staging geometry (hoisted out of K-loop) ----
  // Each wave stages LDS rows [wave*32, wave*32+31] for A and B: two 16-row segments.
  const int srow_in = lane >> 2;      // 0..15
  const int sslot = lane & 3;         // linear 8-elem slot this lane's 16B lands in
  const int row_s0 = wave * 32 + srow_in;
  const int row_s1 = row_s0 + 16;
  const int kc_s0 = sslot ^ ((row_s0 >> 1) & 3);  // global k-chunk to fetch
  const int kc_s1 = sslot ^ ((row_s1 >> 1) & 3);
  // byte offsets (excluding k-step advance): A row stride 1024B, B row stride 2048B
  const size_t offA0b = (size_t)(m0 + row_s0) * 1024 + kc_s0 * 16;
  const size_t offA1b = (size_t)(m0 + row_s1) * 1024 + kc_s1 * 16;
  const size_t offB0b = (size_t)(n0 + row_s0) * 2048 + kc_s0 * 16;
  const size_t offB1b = (size_t)(n0 + row_s1) * 2048 + kc_s1 * 16;
  const int ldsA0 = wave * 1024;        // ushort index: row_s0*32... wave*32 rows *32 ushorts
  const int ldsA1 = ldsA0 + 512;

  auto stage = [&](int buf, int kk) {
    unsigned short* sA = smem + buf * 8192;
    unsigned short* sB = sA + 4096;
    const int k0 = kk * 32;
    const char* Ab = (k0 < 512) ? (const char*)A0 : (const char*)A1;
    const size_t ka = (size_t)(k0 & 511) * 2;   // byte advance within A half
    const size_t kb = (size_t)k0 * 2;           // byte advance within WB row
    gload_lds16(Ab + offA0b + ka, sA + ldsA0);
    gload_lds16(Ab + offA1b + ka, sA + ldsA1);
    gload_lds16((const char*)WB + offB0b + kb, sB + ldsA0);
    gload_lds16((const char*)WB + offB1b + kb, sB + ldsA1);
  };

  // ---- lane-constant fragment-read offsets (ushort indices within a buffer) ----
  const int g = lane >> 4;  // k-chunk this lane group reads
  int rdA[4], rdB[4];
#pragma unroll
  for (int m = 0; m < 4; ++m) {
    int row = wr * 64 + m * 16 + (lane & 15);
    int slot = g ^ ((row >> 1) & 3);
    rdA[m] = row * 32 + slot * 8;
  }
#pragma unroll
  for (int n = 0; n < 4; ++n) {
    int row = wc * 64 + n * 16 + (lane & 15);
    int slot = g ^ ((row >> 1) & 3);
    rdB[n] = row * 32 + slot * 8;
  }

  stage(0, 0);
  int cur = 0;
  const int NK = 32;  // K=1024 / BK=32
  for (int kk = 0; kk < NK; ++kk) {
    __syncthreads();  // drains vmcnt -> buf[cur] staged; all waves done with buf[cur^1]
    if (kk + 1 < NK) stage(cur ^ 1, kk + 1);
    unsigned short* sA = smem + cur * 8192;
    unsigned short* sB = sA + 4096;
    bf16x8 aF[4], bF[4];
#pragma unroll
    for (int m = 0; m < 4; ++m) aF[m] = *(const bf16x8*)(sA + rdA[m]);
#pragma unroll
    for (int n = 0; n < 4; ++n) bF[n] = *(const bf16x8*)(sB + rdB[n]);
#pragma unroll
    for (int m = 0; m < 4; ++m)
#pragma unroll
      for (int n = 0; n < 4; ++n)
        acc[m][n] = __builtin_amdgcn_mfma_f32_16x16x32_bf16(aF[m], bF[n], acc[m][n], 0, 0, 0);
    cur ^= 1;
  }

  // epilogue: C/D layout col=lane&15, row=(lane>>4)*4+r
#pragma unroll
  for (int n = 0; n < 4; ++n) {
    int coln = n0 + wc * 64 + n * 16 + (lane & 15);
    float bv = bias[coln];
#pragma unroll
    for (int m = 0; m < 4; ++m) {
      int rbase = m0 + wr * 64 + m * 16 + (lane >> 4) * 4;
#pragma unroll
      for (int r = 0; r < 4; ++r) {
        int row = rbase + r;
        if (row < M) {
          float v = acc[m][n][r] + bv;
          if (RELU) v = fmaxf(v, 0.f);
          out[(size_t)row * 512 + coln] = (OT)v;
        }
      }
    }
  }
}

extern "C" void kernel_launch(void* const* d_in, const int* in_sizes, int n_in,
                              void* d_out, int out_size, void* d_ws, size_t ws_size,
                              hipStream_t stream) {
  const float* x   = (const float*)d_in[0];
  const int*   ei  = (const int*)d_in[1];
  const float* Wl1 = (const float*)d_in[2];
  const float* Wr1 = (const float*)d_in[3];
  const float* b1  = (const float*)d_in[4];
  const float* Wl2 = (const float*)d_in[5];
  const float* Wr2 = (const float*)d_in[6];
  const float* b2  = (const float*)d_in[7];

  const int N = in_sizes[0] / 512;            // 50000
  const int E = in_sizes[1] / 2;              // 800000
  const int NPAD = ((N + 127) / 128) * 128;   // 50048
  const int* srcp = ei;
  const int* dstp = ei + E;

  char* ws = (char*)d_ws;
  size_t off = 0;
  auto alloc = [&](size_t sz) -> char* {
    char* p = ws + off;
    off += sz;
    off = (off + 255) & ~(size_t)255;
    return p;
  };

  bf16_t* xb    = (bf16_t*)alloc((size_t)NPAD * 512 * 2);
  bf16_t* hb    = (bf16_t*)alloc((size_t)NPAD * 512 * 2);
  bf16_t* meanb = (bf16_t*)alloc((size_t)NPAD * 512 * 2);
  bf16_t* WB1   = (bf16_t*)alloc((size_t)512 * 1024 * 2);
  bf16_t* WB2   = (bf16_t*)alloc((size_t)512 * 1024 * 2);
  int* deg      = (int*)alloc((size_t)N * 4);
  int* rowS     = (int*)alloc((size_t)(N + 8) * 4);
  int* cursor   = (int*)alloc((size_t)N * 4);
  int* partial  = (int*)alloc(4096);
  int* colb     = (int*)alloc((size_t)E * 4);
  (void)ws_size; (void)n_in; (void)out_size;

  hipMemsetAsync(deg, 0, (size_t)N * 4, stream);

  {
    int total = NPAD * 512, valid = N * 512;
    cvt_x_k<<<dim3((total / 8 + 255) / 256), dim3(256), 0, stream>>>(x, xb, total, valid);
  }
  cvt_w_k<<<dim3(256), dim3(256), 0, stream>>>(Wl1, Wr1, WB1);
  cvt_w_k<<<dim3(256), dim3(256), 0, stream>>>(Wl2, Wr2, WB2);

  deg_k<<<dim3((E + 255) / 256), dim3(256), 0, stream>>>(dstp, deg, E);

  int NB = (N + 511) / 512;  // 98
  scan_part_k<<<dim3(NB), dim3(512), 0, stream>>>(deg, partial, N);
  scan_off_k<<<dim3(1), dim3(64), 0, stream>>>(partial, NB, rowS, N);
  scan_blk_k<<<dim3(NB), dim3(512), 0, stream>>>(deg, partial, rowS, cursor, N);
  scat_k<<<dim3((E + 255) / 256), dim3(256), 0, stream>>>(srcp, dstp, cursor, colb, E);

  // layer 1
  agg_k<<<dim3(NPAD / 4), dim3(256), 0, stream>>>(xb, rowS, colb, meanb, N, NPAD);
  dim3 grid(4, NPAD / 128);
  gemm_k<true, bf16_t><<<grid, dim3(256), 0, stream>>>(meanb, xb, WB1, b1, hb, N);

  // layer 2
  agg_k<<<dim3(NPAD / 4), dim3(256), 0, stream>>>(hb, rowS, colb, meanb, N, NPAD);
  gemm_k<false, float><<<grid, dim3(256), 0, stream>>>(meanb, hb, WB2, b2, (float*)d_out, N);
}

// Round 4
// 554.031 us; speedup vs baseline: 1.0277x; 1.0277x over previous
//
#include <hip/hip_runtime.h>

typedef __bf16 bf16_t;
typedef __bf16 bf16x8 __attribute__((ext_vector_type(8)));
typedef float  f32x4  __attribute__((ext_vector_type(4)));

#define D_FEAT 512

// ---------------- convert x (f32) -> padded bf16 ----------------
__global__ void cvt_x_k(const float* __restrict__ x, bf16_t* __restrict__ xb,
                        int total, int valid) {
  int idx = (blockIdx.x * 256 + threadIdx.x) * 8;
  if (idx >= total) return;
  bf16x8 o;
  if (idx < valid) {
    const float4* p = (const float4*)(x + idx);
    float4 a = p[0], b = p[1];
    o[0] = (bf16_t)a.x; o[1] = (bf16_t)a.y; o[2] = (bf16_t)a.z; o[3] = (bf16_t)a.w;
    o[4] = (bf16_t)b.x; o[5] = (bf16_t)b.y; o[6] = (bf16_t)b.z; o[7] = (bf16_t)b.w;
  } else {
#pragma unroll
    for (int i = 0; i < 8; ++i) o[i] = (bf16_t)0.f;
  }
  *(bf16x8*)(xb + idx) = o;
}

// ------------- build combined weight WB[n][k] (bf16, [512][1024]) -------------
__global__ void cvt_w_k(const float* __restrict__ Wl, const float* __restrict__ Wr,
                        bf16_t* __restrict__ WB) {
  int idx = (blockIdx.x * 256 + threadIdx.x) * 8;  // into [512][1024]
  int n = idx >> 10, k = idx & 1023;
  const float* s = (k < 512) ? (Wl + n * 512 + k) : (Wr + n * 512 + k - 512);
  const float4* p = (const float4*)s;
  float4 a = p[0], b = p[1];
  bf16x8 o;
  o[0] = (bf16_t)a.x; o[1] = (bf16_t)a.y; o[2] = (bf16_t)a.z; o[3] = (bf16_t)a.w;
  o[4] = (bf16_t)b.x; o[5] = (bf16_t)b.y; o[6] = (bf16_t)b.z; o[7] = (bf16_t)b.w;
  *(bf16x8*)(WB + idx) = o;
}

// ---------------- CSR build ----------------
__global__ void deg_k(const int* __restrict__ dst, int* __restrict__ deg, int E) {
  int e = blockIdx.x * 256 + threadIdx.x;
  if (e < E) atomicAdd(&deg[dst[e]], 1);
}

__global__ void scan_part_k(const int* __restrict__ deg, int* __restrict__ partial, int N) {
  __shared__ int sd[512];
  int tid = threadIdx.x;
  int i = blockIdx.x * 512 + tid;
  sd[tid] = (i < N) ? deg[i] : 0;
  __syncthreads();
  for (int s = 256; s > 0; s >>= 1) {
    if (tid < s) sd[tid] += sd[tid + s];
    __syncthreads();
  }
  if (tid == 0) partial[blockIdx.x] = sd[0];
}

// parallel one-block exclusive scan over nb (<=128) block partials
__global__ void scan_off_k(int* __restrict__ partial, int nb, int* __restrict__ rowS, int N) {
  __shared__ int sd[128];
  int tid = threadIdx.x;  // 128 threads
  int v = (tid < nb) ? partial[tid] : 0;
  sd[tid] = v;
  __syncthreads();
#pragma unroll
  for (int offd = 1; offd < 128; offd <<= 1) {
    int t = (tid >= offd) ? sd[tid - offd] : 0;
    __syncthreads();
    sd[tid] += t;
    __syncthreads();
  }
  if (tid < nb) partial[tid] = sd[tid] - v;  // exclusive
  if (tid == nb - 1) rowS[N] = sd[tid];      // total
}

__global__ void scan_blk_k(const int* __restrict__ deg, const int* __restrict__ partial,
                           int* __restrict__ rowS, int* __restrict__ cursor, int N) {
  __shared__ int sd[512];
  int tid = threadIdx.x;
  int i = blockIdx.x * 512 + tid;
  int v = (i < N) ? deg[i] : 0;
  sd[tid] = v;
  __syncthreads();
  for (int offd = 1; offd < 512; offd <<= 1) {
    int t = (tid >= offd) ? sd[tid - offd] : 0;
    __syncthreads();
    sd[tid] += t;
    __syncthreads();
  }
  int excl = sd[tid] - v + partial[blockIdx.x];
  if (i < N) { rowS[i] = excl; cursor[i] = excl; }
}

__global__ void scat_k(const int* __restrict__ src, const int* __restrict__ dst,
                       int* __restrict__ cursor, int* __restrict__ col, int E) {
  int e = blockIdx.x * 256 + threadIdx.x;
  if (e < E) {
    int d = dst[e];
    int p = atomicAdd(&cursor[d], 1);
    col[p] = src[e];
  }
}

// ---------------- mean aggregation: out[i] = mean_{j in N(i)} X[col[j]] ----------------
__global__ __launch_bounds__(256) void agg_k(const bf16_t* __restrict__ X,
                                             const int* __restrict__ rs,
                                             const int* __restrict__ col,
                                             bf16_t* __restrict__ out,
                                             int N, int NPAD) {
  const int lane = threadIdx.x & 63;
  const int node = blockIdx.x * 4 + (threadIdx.x >> 6);
  if (node >= NPAD) return;
  const size_t obase = (size_t)node * D_FEAT + lane * 8;
  bf16x8 o;
  if (node >= N) {
#pragma unroll
    for (int i = 0; i < 8; ++i) o[i] = (bf16_t)0.f;
    *(bf16x8*)(out + obase) = o;
    return;
  }
  const int s = rs[node], e = rs[node + 1];
  const int loff = lane * 8;
  float acc[8] = {0.f, 0.f, 0.f, 0.f, 0.f, 0.f, 0.f, 0.f};
  int j = s;
  for (; j + 8 <= e; j += 8) {
    int c0 = col[j + 0], c1 = col[j + 1], c2 = col[j + 2], c3 = col[j + 3];
    int c4 = col[j + 4], c5 = col[j + 5], c6 = col[j + 6], c7 = col[j + 7];
    bf16x8 v0 = *(const bf16x8*)(X + (size_t)c0 * D_FEAT + loff);
    bf16x8 v1 = *(const bf16x8*)(X + (size_t)c1 * D_FEAT + loff);
    bf16x8 v2 = *(const bf16x8*)(X + (size_t)c2 * D_FEAT + loff);
    bf16x8 v3 = *(const bf16x8*)(X + (size_t)c3 * D_FEAT + loff);
    bf16x8 v4 = *(const bf16x8*)(X + (size_t)c4 * D_FEAT + loff);
    bf16x8 v5 = *(const bf16x8*)(X + (size_t)c5 * D_FEAT + loff);
    bf16x8 v6 = *(const bf16x8*)(X + (size_t)c6 * D_FEAT + loff);
    bf16x8 v7 = *(const bf16x8*)(X + (size_t)c7 * D_FEAT + loff);
#pragma unroll
    for (int i = 0; i < 8; ++i) {
      float s01 = (float)v0[i] + (float)v1[i];
      float s23 = (float)v2[i] + (float)v3[i];
      float s45 = (float)v4[i] + (float)v5[i];
      float s67 = (float)v6[i] + (float)v7[i];
      acc[i] += (s01 + s23) + (s45 + s67);
    }
  }
  for (; j + 2 <= e; j += 2) {
    int c0 = col[j + 0], c1 = col[j + 1];
    bf16x8 v0 = *(const bf16x8*)(X + (size_t)c0 * D_FEAT + loff);
    bf16x8 v1 = *(const bf16x8*)(X + (size_t)c1 * D_FEAT + loff);
#pragma unroll
    for (int i = 0; i < 8; ++i) acc[i] += (float)v0[i] + (float)v1[i];
  }
  for (; j < e; ++j) {
    int c0 = col[j];
    bf16x8 v0 = *(const bf16x8*)(X + (size_t)c0 * D_FEAT + loff);
#pragma unroll
    for (int i = 0; i < 8; ++i) acc[i] += (float)v0[i];
  }
  float sc = (e > s) ? 1.0f / (float)(e - s) : 0.f;
#pragma unroll
  for (int i = 0; i < 8; ++i) o[i] = (bf16_t)(acc[i] * sc);
  *(bf16x8*)(out + obase) = o;
}

// ---------------- fused GEMM: out[m][n] = sum_k [A0|A1][m][k] * WB[n][k] + bias[n] ----------------
// 128x128 tile, BK=32, 4 waves (2x2), 16x16x32 bf16 MFMA, double-buffered LDS.
// XCD-aware 1-D grid remap: all 4 n-tiles of one m-tile land on the SAME XCD,
// back-to-back -> A m-tile fetched over fabric once instead of 4x.
__device__ __forceinline__ void gload_lds16(const void* g, void* l) {
  __builtin_amdgcn_global_load_lds(
      (const __attribute__((address_space(1))) unsigned int*)g,
      (__attribute__((address_space(3))) unsigned int*)l,
      16, 0, 0);
}

#define M_TILES 391   // ceil(50048/128)
#define M_TILES_PAD 400  // 400*4 = 1600 blocks, divisible by 8 XCDs

template <bool RELU, typename OT>
__global__ __launch_bounds__(256) void gemm_k(
    const bf16_t* __restrict__ A0,   // K 0..511   (mean features)
    const bf16_t* __restrict__ A1,   // K 512..1023 (self features)
    const bf16_t* __restrict__ WB,   // [512][1024]
    const float* __restrict__ bias,  // [512]
    OT* __restrict__ out, int M) {
  // XCD-aware decomposition (hardware round-robins blockIdx over 8 XCDs):
  // x = bid%8 (XCD), k = bid/8 (position in that XCD's stream);
  // m = x + 8*(k>>2) keeps the 4 n-tiles of one m consecutive on one XCD.
  const int bid = blockIdx.x;
  const int xcd = bid & 7;
  const int kpos = bid >> 3;
  const int mt = xcd + 8 * (kpos >> 2);
  const int nt = kpos & 3;
  if (mt >= M_TILES) return;

  __shared__ __align__(16) unsigned short smem[2 * 8192];  // per buf: A 4096 + B 4096 ushorts

  const int tid = threadIdx.x;
  const int lane = tid & 63;
  const int wave = tid >> 6;
  const int wr = wave >> 1, wc = wave & 1;
  const int m0 = mt * 128;
  const int n0 = nt * 128;

  f32x4 acc[4][4];
#pragma unroll
  for (int m = 0; m < 4; ++m)
#pragma unroll
    for (int n = 0; n < 4; ++n) acc[m][n] = (f32x4){0.f, 0.f, 0.f, 0.f};

  // ---- lane-constant staging geometry (hoisted out of K-loop) ----
  const int srow_in = lane >> 2;      // 0..15
  const int sslot = lane & 3;         // linear 8-elem slot this lane's 16B lands in
  const int row_s0 = wave * 32 + srow_in;
  const int row_s1 = row_s0 + 16;
  const int kc_s0 = sslot ^ ((row_s0 >> 1) & 3);  // global k-chunk to fetch
  const int kc_s1 = sslot ^ ((row_s1 >> 1) & 3);
  const size_t offA0b = (size_t)(m0 + row_s0) * 1024 + kc_s0 * 16;
  const size_t offA1b = (size_t)(m0 + row_s1) * 1024 + kc_s1 * 16;
  const size_t offB0b = (size_t)(n0 + row_s0) * 2048 + kc_s0 * 16;
  const size_t offB1b = (size_t)(n0 + row_s1) * 2048 + kc_s1 * 16;
  const int ldsA0 = wave * 1024;
  const int ldsA1 = ldsA0 + 512;

  auto stage = [&](int buf, int kk) {
    unsigned short* sA = smem + buf * 8192;
    unsigned short* sB = sA + 4096;
    const int k0 = kk * 32;
    const char* Ab = (k0 < 512) ? (const char*)A0 : (const char*)A1;
    const size_t ka = (size_t)(k0 & 511) * 2;
    const size_t kb = (size_t)k0 * 2;
    gload_lds16(Ab + offA0b + ka, sA + ldsA0);
    gload_lds16(Ab + offA1b + ka, sA + ldsA1);
    gload_lds16((const char*)WB + offB0b + kb, sB + ldsA0);
    gload_lds16((const char*)WB + offB1b + kb, sB + ldsA1);
  };

  // ---- lane-constant fragment-read offsets ----
  const int g = lane >> 4;
  int rdA[4], rdB[4];
#pragma unroll
  for (int m = 0; m < 4; ++m) {
    int row = wr * 64 + m * 16 + (lane & 15);
    int slot = g ^ ((row >> 1) & 3);
    rdA[m] = row * 32 + slot * 8;
  }
#pragma unroll
  for (int n = 0; n < 4; ++n) {
    int row = wc * 64 + n * 16 + (lane & 15);
    int slot = g ^ ((row >> 1) & 3);
    rdB[n] = row * 32 + slot * 8;
  }

  stage(0, 0);
  int cur = 0;
  const int NK = 32;  // K=1024 / BK=32
  for (int kk = 0; kk < NK; ++kk) {
    __syncthreads();
    if (kk + 1 < NK) stage(cur ^ 1, kk + 1);
    unsigned short* sA = smem + cur * 8192;
    unsigned short* sB = sA + 4096;
    bf16x8 aF[4], bF[4];
#pragma unroll
    for (int m = 0; m < 4; ++m) aF[m] = *(const bf16x8*)(sA + rdA[m]);
#pragma unroll
    for (int n = 0; n < 4; ++n) bF[n] = *(const bf16x8*)(sB + rdB[n]);
#pragma unroll
    for (int m = 0; m < 4; ++m)
#pragma unroll
      for (int n = 0; n < 4; ++n)
        acc[m][n] = __builtin_amdgcn_mfma_f32_16x16x32_bf16(aF[m], bF[n], acc[m][n], 0, 0, 0);
    cur ^= 1;
  }

  // epilogue: C/D layout col=lane&15, row=(lane>>4)*4+r
#pragma unroll
  for (int n = 0; n < 4; ++n) {
    int coln = n0 + wc * 64 + n * 16 + (lane & 15);
    float bv = bias[coln];
#pragma unroll
    for (int m = 0; m < 4; ++m) {
      int rbase = m0 + wr * 64 + m * 16 + (lane >> 4) * 4;
#pragma unroll
      for (int r = 0; r < 4; ++r) {
        int row = rbase + r;
        if (row < M) {
          float v = acc[m][n][r] + bv;
          if (RELU) v = fmaxf(v, 0.f);
          out[(size_t)row * 512 + coln] = (OT)v;
        }
      }
    }
  }
}

extern "C" void kernel_launch(void* const* d_in, const int* in_sizes, int n_in,
                              void* d_out, int out_size, void* d_ws, size_t ws_size,
                              hipStream_t stream) {
  const float* x   = (const float*)d_in[0];
  const int*   ei  = (const int*)d_in[1];
  const float* Wl1 = (const float*)d_in[2];
  const float* Wr1 = (const float*)d_in[3];
  const float* b1  = (const float*)d_in[4];
  const float* Wl2 = (const float*)d_in[5];
  const float* Wr2 = (const float*)d_in[6];
  const float* b2  = (const float*)d_in[7];

  const int N = in_sizes[0] / 512;            // 50000
  const int E = in_sizes[1] / 2;              // 800000
  const int NPAD = ((N + 127) / 128) * 128;   // 50048
  const int* srcp = ei;
  const int* dstp = ei + E;

  char* ws = (char*)d_ws;
  size_t off = 0;
  auto alloc = [&](size_t sz) -> char* {
    char* p = ws + off;
    off += sz;
    off = (off + 255) & ~(size_t)255;
    return p;
  };

  bf16_t* xb    = (bf16_t*)alloc((size_t)NPAD * 512 * 2);
  bf16_t* hb    = (bf16_t*)alloc((size_t)NPAD * 512 * 2);
  bf16_t* meanb = (bf16_t*)alloc((size_t)NPAD * 512 * 2);
  bf16_t* WB1   = (bf16_t*)alloc((size_t)512 * 1024 * 2);
  bf16_t* WB2   = (bf16_t*)alloc((size_t)512 * 1024 * 2);
  int* deg      = (int*)alloc((size_t)N * 4);
  int* rowS     = (int*)alloc((size_t)(N + 8) * 4);
  int* cursor   = (int*)alloc((size_t)N * 4);
  int* partial  = (int*)alloc(4096);
  int* colb     = (int*)alloc((size_t)E * 4);
  (void)ws_size; (void)n_in; (void)out_size;

  hipMemsetAsync(deg, 0, (size_t)N * 4, stream);

  {
    int total = NPAD * 512, valid = N * 512;
    cvt_x_k<<<dim3((total / 8 + 255) / 256), dim3(256), 0, stream>>>(x, xb, total, valid);
  }
  cvt_w_k<<<dim3(256), dim3(256), 0, stream>>>(Wl1, Wr1, WB1);
  cvt_w_k<<<dim3(256), dim3(256), 0, stream>>>(Wl2, Wr2, WB2);

  deg_k<<<dim3((E + 255) / 256), dim3(256), 0, stream>>>(dstp, deg, E);

  int NB = (N + 511) / 512;  // 98
  scan_part_k<<<dim3(NB), dim3(512), 0, stream>>>(deg, partial, N);
  scan_off_k<<<dim3(1), dim3(128), 0, stream>>>(partial, NB, rowS, N);
  scan_blk_k<<<dim3(NB), dim3(512), 0, stream>>>(deg, partial, rowS, cursor, N);
  scat_k<<<dim3((E + 255) / 256), dim3(256), 0, stream>>>(srcp, dstp, cursor, colb, E);

  // layer 1
  agg_k<<<dim3(NPAD / 4), dim3(256), 0, stream>>>(xb, rowS, colb, meanb, N, NPAD);
  dim3 grid(M_TILES_PAD * 4);
  gemm_k<true, bf16_t><<<grid, dim3(256), 0, stream>>>(meanb, xb, WB1, b1, hb, N);

  // layer 2
  agg_k<<<dim3(NPAD / 4), dim3(256), 0, stream>>>(hb, rowS, colb, meanb, N, NPAD);
  gemm_k<false, float><<<grid, dim3(256), 0, stream>>>(meanb, hb, WB2, b2, (float*)d_out, N);
}

// Round 5
// 549.061 us; speedup vs baseline: 1.0370x; 1.0091x over previous
//
#include <hip/hip_runtime.h>

typedef __bf16 bf16_t;
typedef __bf16 bf16x8 __attribute__((ext_vector_type(8)));
typedef float  f32x4  __attribute__((ext_vector_type(4)));

#define D_FEAT 512
#define BM 256
#define BN 128
#define BKK 64
#define M_TILES 196            // 196*256 = 50176 rows (padded)
#define NPAD2 (M_TILES * 256)
#define N_TILES 4              // 512 / 128
#define GEMM_BLOCKS (M_TILES * N_TILES)  // 784 = 8*98

// ---------------- convert x (f32) -> padded bf16 ----------------
__global__ void cvt_x_k(const float* __restrict__ x, bf16_t* __restrict__ xb,
                        int total, int valid) {
  int idx = (blockIdx.x * 256 + threadIdx.x) * 8;
  if (idx >= total) return;
  bf16x8 o;
  if (idx < valid) {
    const float4* p = (const float4*)(x + idx);
    float4 a = p[0], b = p[1];
    o[0] = (bf16_t)a.x; o[1] = (bf16_t)a.y; o[2] = (bf16_t)a.z; o[3] = (bf16_t)a.w;
    o[4] = (bf16_t)b.x; o[5] = (bf16_t)b.y; o[6] = (bf16_t)b.z; o[7] = (bf16_t)b.w;
  } else {
#pragma unroll
    for (int i = 0; i < 8; ++i) o[i] = (bf16_t)0.f;
  }
  *(bf16x8*)(xb + idx) = o;
}

// ------------- build combined weight WB[n][k] (bf16, [512][1024]) -------------
__global__ void cvt_w_k(const float* __restrict__ Wl, const float* __restrict__ Wr,
                        bf16_t* __restrict__ WB) {
  int idx = (blockIdx.x * 256 + threadIdx.x) * 8;  // into [512][1024]
  int n = idx >> 10, k = idx & 1023;
  const float* s = (k < 512) ? (Wl + n * 512 + k) : (Wr + n * 512 + k - 512);
  const float4* p = (const float4*)s;
  float4 a = p[0], b = p[1];
  bf16x8 o;
  o[0] = (bf16_t)a.x; o[1] = (bf16_t)a.y; o[2] = (bf16_t)a.z; o[3] = (bf16_t)a.w;
  o[4] = (bf16_t)b.x; o[5] = (bf16_t)b.y; o[6] = (bf16_t)b.z; o[7] = (bf16_t)b.w;
  *(bf16x8*)(WB + idx) = o;
}

// ---------------- CSR build ----------------
__global__ void deg_k(const int* __restrict__ dst, int* __restrict__ deg, int E) {
  int e = blockIdx.x * 256 + threadIdx.x;
  if (e < E) atomicAdd(&deg[dst[e]], 1);
}

__global__ void scan_part_k(const int* __restrict__ deg, int* __restrict__ partial, int N) {
  __shared__ int sd[512];
  int tid = threadIdx.x;
  int i = blockIdx.x * 512 + tid;
  sd[tid] = (i < N) ? deg[i] : 0;
  __syncthreads();
  for (int s = 256; s > 0; s >>= 1) {
    if (tid < s) sd[tid] += sd[tid + s];
    __syncthreads();
  }
  if (tid == 0) partial[blockIdx.x] = sd[0];
}

// parallel one-block exclusive scan over nb (<=128) block partials
__global__ void scan_off_k(int* __restrict__ partial, int nb, int* __restrict__ rowS, int N) {
  __shared__ int sd[128];
  int tid = threadIdx.x;  // 128 threads
  int v = (tid < nb) ? partial[tid] : 0;
  sd[tid] = v;
  __syncthreads();
#pragma unroll
  for (int offd = 1; offd < 128; offd <<= 1) {
    int t = (tid >= offd) ? sd[tid - offd] : 0;
    __syncthreads();
    sd[tid] += t;
    __syncthreads();
  }
  if (tid < nb) partial[tid] = sd[tid] - v;  // exclusive
  if (tid == nb - 1) rowS[N] = sd[tid];      // total
}

__global__ void scan_blk_k(const int* __restrict__ deg, const int* __restrict__ partial,
                           int* __restrict__ rowS, int* __restrict__ cursor, int N) {
  __shared__ int sd[512];
  int tid = threadIdx.x;
  int i = blockIdx.x * 512 + tid;
  int v = (i < N) ? deg[i] : 0;
  sd[tid] = v;
  __syncthreads();
  for (int offd = 1; offd < 512; offd <<= 1) {
    int t = (tid >= offd) ? sd[tid - offd] : 0;
    __syncthreads();
    sd[tid] += t;
    __syncthreads();
  }
  int excl = sd[tid] - v + partial[blockIdx.x];
  if (i < N) { rowS[i] = excl; cursor[i] = excl; }
}

__global__ void scat_k(const int* __restrict__ src, const int* __restrict__ dst,
                       int* __restrict__ cursor, int* __restrict__ col, int E) {
  int e = blockIdx.x * 256 + threadIdx.x;
  if (e < E) {
    int d = dst[e];
    int p = atomicAdd(&cursor[d], 1);
    col[p] = src[e];
  }
}

// ---------------- mean aggregation: out[i] = mean_{j in N(i)} X[col[j]] ----------------
__global__ __launch_bounds__(256) void agg_k(const bf16_t* __restrict__ X,
                                             const int* __restrict__ rs,
                                             const int* __restrict__ col,
                                             bf16_t* __restrict__ out,
                                             int N, int NPAD) {
  const int lane = threadIdx.x & 63;
  const int node = blockIdx.x * 4 + (threadIdx.x >> 6);
  if (node >= NPAD) return;
  const size_t obase = (size_t)node * D_FEAT + lane * 8;
  bf16x8 o;
  if (node >= N) {
#pragma unroll
    for (int i = 0; i < 8; ++i) o[i] = (bf16_t)0.f;
    *(bf16x8*)(out + obase) = o;
    return;
  }
  const int s = rs[node], e = rs[node + 1];
  const int loff = lane * 8;
  float acc[8] = {0.f, 0.f, 0.f, 0.f, 0.f, 0.f, 0.f, 0.f};
  int j = s;
  for (; j + 8 <= e; j += 8) {
    int c0 = col[j + 0], c1 = col[j + 1], c2 = col[j + 2], c3 = col[j + 3];
    int c4 = col[j + 4], c5 = col[j + 5], c6 = col[j + 6], c7 = col[j + 7];
    bf16x8 v0 = *(const bf16x8*)(X + (size_t)c0 * D_FEAT + loff);
    bf16x8 v1 = *(const bf16x8*)(X + (size_t)c1 * D_FEAT + loff);
    bf16x8 v2 = *(const bf16x8*)(X + (size_t)c2 * D_FEAT + loff);
    bf16x8 v3 = *(const bf16x8*)(X + (size_t)c3 * D_FEAT + loff);
    bf16x8 v4 = *(const bf16x8*)(X + (size_t)c4 * D_FEAT + loff);
    bf16x8 v5 = *(const bf16x8*)(X + (size_t)c5 * D_FEAT + loff);
    bf16x8 v6 = *(const bf16x8*)(X + (size_t)c6 * D_FEAT + loff);
    bf16x8 v7 = *(const bf16x8*)(X + (size_t)c7 * D_FEAT + loff);
#pragma unroll
    for (int i = 0; i < 8; ++i) {
      float s01 = (float)v0[i] + (float)v1[i];
      float s23 = (float)v2[i] + (float)v3[i];
      float s45 = (float)v4[i] + (float)v5[i];
      float s67 = (float)v6[i] + (float)v7[i];
      acc[i] += (s01 + s23) + (s45 + s67);
    }
  }
  for (; j + 2 <= e; j += 2) {
    int c0 = col[j + 0], c1 = col[j + 1];
    bf16x8 v0 = *(const bf16x8*)(X + (size_t)c0 * D_FEAT + loff);
    bf16x8 v1 = *(const bf16x8*)(X + (size_t)c1 * D_FEAT + loff);
#pragma unroll
    for (int i = 0; i < 8; ++i) acc[i] += (float)v0[i] + (float)v1[i];
  }
  for (; j < e; ++j) {
    int c0 = col[j];
    bf16x8 v0 = *(const bf16x8*)(X + (size_t)c0 * D_FEAT + loff);
#pragma unroll
    for (int i = 0; i < 8; ++i) acc[i] += (float)v0[i];
  }
  float sc = (e > s) ? 1.0f / (float)(e - s) : 0.f;
#pragma unroll
  for (int i = 0; i < 8; ++i) o[i] = (bf16_t)(acc[i] * sc);
  *(bf16x8*)(out + obase) = o;
}

// ---------------- fused GEMM: out[m][n] = sum_k [A0|A1][m][k] * WB[n][k] + bias[n] ----------------
// BM=256 x BN=128 tile, BK=64, 8 waves (4M x 2N, per-wave C 64x64), 2-phase
// double-buffered LDS (96 KB), global_load_lds w/ source-side XOR swizzle.
// LDS[row][s] holds global k-chunk (s ^ (row&7)); involution applied on the
// global source at stage time and on the ds_read slot -> 2-way banked reads (free).
__device__ __forceinline__ void gload_lds16(const void* g, void* l) {
  __builtin_amdgcn_global_load_lds(
      (const __attribute__((address_space(1))) unsigned int*)g,
      (__attribute__((address_space(3))) unsigned int*)l,
      16, 0, 0);
}

template <bool RELU, typename OT>
__global__ __launch_bounds__(512, 2) void gemm_k(
    const bf16_t* __restrict__ A0,   // K 0..511   (mean features), NPAD2 rows
    const bf16_t* __restrict__ A1,   // K 512..1023 (self features), NPAD2 rows
    const bf16_t* __restrict__ WB,   // [512][1024]
    const float* __restrict__ bias,  // [512]
    OT* __restrict__ out, int M) {
  // XCD-chunked bijective remap: 784 blocks = 8 XCDs x 98; the 4 n-tiles of one
  // m-tile stay consecutive on one XCD -> A tile L2-hits after first n-block.
  const int t = (blockIdx.x & 7) * (GEMM_BLOCKS / 8) + (blockIdx.x >> 3);
  const int mt = t >> 2;
  const int nt = t & 3;

  // per buf: A 256x64 (16384 us) + B 128x64 (8192 us) = 48 KB; x2 bufs = 96 KB
  __shared__ __align__(16) unsigned short smem[2 * 24576];

  const int tid = threadIdx.x;
  const int lane = tid & 63;
  const int wave = tid >> 6;
  const int wm = wave >> 1;            // 0..3
  const int wn = wave & 1;             // 0..1
  const int m0 = mt * BM;
  const int n0 = nt * BN;

  f32x4 acc[4][4];
#pragma unroll
  for (int m = 0; m < 4; ++m)
#pragma unroll
    for (int n = 0; n < 4; ++n) acc[m][n] = (f32x4){0.f, 0.f, 0.f, 0.f};

  // ---- staging geometry (lane-constant, hoisted) ----
  const int srow = tid >> 3;           // 0..63
  const int sslot = tid & 7;           // 0..7 (16B slots per 128B row)
  const int kc = sslot ^ (srow & 7);   // global k-chunk this lane fetches
  const int ldsBase = srow * 64 + sslot * 8;  // ushort idx; +l*4096 per segment
  // global byte offsets (sans k-step advance): A row stride 1024B, B 2048B
  size_t gA[4], gB[2];
#pragma unroll
  for (int l = 0; l < 4; ++l) gA[l] = (size_t)(m0 + l * 64 + srow) * 1024 + kc * 16;
#pragma unroll
  for (int l = 0; l < 2; ++l) gB[l] = (size_t)(n0 + l * 64 + srow) * 2048 + kc * 16;

  auto stage = [&](int buf, int kk) {
    unsigned short* sA = smem + buf * 24576;
    unsigned short* sB = sA + 16384;
    const int k0 = kk * BKK;
    const char* Ab = (k0 < 512) ? (const char*)A0 : (const char*)A1;
    const size_t ka = (size_t)(k0 & 511) * 2;
    const size_t kb = (size_t)k0 * 2;
#pragma unroll
    for (int l = 0; l < 4; ++l) gload_lds16(Ab + gA[l] + ka, sA + ldsBase + l * 4096);
#pragma unroll
    for (int l = 0; l < 2; ++l) gload_lds16((const char*)WB + gB[l] + kb, sB + ldsBase + l * 4096);
  };

  // ---- fragment-read offsets (ushort indices), ks = k-slice (0/1), 8 frags each ----
  const int fr = lane & 15;
  const int g = lane >> 4;
  int rdA[2][4], rdB[2][4];
#pragma unroll
  for (int ks = 0; ks < 2; ++ks) {
    const int sl = ((ks * 4 + g) ^ (fr & 7)) * 8;
#pragma unroll
    for (int m = 0; m < 4; ++m) rdA[ks][m] = (wm * 64 + m * 16 + fr) * 64 + sl;
#pragma unroll
    for (int n = 0; n < 4; ++n) rdB[ks][n] = (wn * 64 + n * 16 + fr) * 64 + sl;
  }

  stage(0, 0);
  int cur = 0;
  const int NK = 1024 / BKK;  // 16
  for (int kk = 0; kk < NK; ++kk) {
    __syncthreads();  // implicit vmcnt(0)+lgkmcnt(0) drain: buf[cur] staged, buf[cur^1] free
    if (kk + 1 < NK) stage(cur ^ 1, kk + 1);
    unsigned short* sA = smem + cur * 24576;
    unsigned short* sB = sA + 16384;
#pragma unroll
    for (int ks = 0; ks < 2; ++ks) {
      bf16x8 aF[4], bF[4];
#pragma unroll
      for (int m = 0; m < 4; ++m) aF[m] = *(const bf16x8*)(sA + rdA[ks][m]);
#pragma unroll
      for (int n = 0; n < 4; ++n) bF[n] = *(const bf16x8*)(sB + rdB[ks][n]);
#pragma unroll
      for (int m = 0; m < 4; ++m)
#pragma unroll
        for (int n = 0; n < 4; ++n)
          acc[m][n] = __builtin_amdgcn_mfma_f32_16x16x32_bf16(aF[m], bF[n], acc[m][n], 0, 0, 0);
    }
    cur ^= 1;
  }

  // epilogue: C/D layout col=lane&15, row=(lane>>4)*4+r
#pragma unroll
  for (int n = 0; n < 4; ++n) {
    int coln = n0 + wn * 64 + n * 16 + fr;
    float bv = bias[coln];
#pragma unroll
    for (int m = 0; m < 4; ++m) {
      int rbase = m0 + wm * 64 + m * 16 + g * 4;
#pragma unroll
      for (int r = 0; r < 4; ++r) {
        int row = rbase + r;
        if (row < M) {
          float v = acc[m][n][r] + bv;
          if (RELU) v = fmaxf(v, 0.f);
          out[(size_t)row * 512 + coln] = (OT)v;
        }
      }
    }
  }
}

extern "C" void kernel_launch(void* const* d_in, const int* in_sizes, int n_in,
                              void* d_out, int out_size, void* d_ws, size_t ws_size,
                              hipStream_t stream) {
  const float* x   = (const float*)d_in[0];
  const int*   ei  = (const int*)d_in[1];
  const float* Wl1 = (const float*)d_in[2];
  const float* Wr1 = (const float*)d_in[3];
  const float* b1  = (const float*)d_in[4];
  const float* Wl2 = (const float*)d_in[5];
  const float* Wr2 = (const float*)d_in[6];
  const float* b2  = (const float*)d_in[7];

  const int N = in_sizes[0] / 512;            // 50000
  const int E = in_sizes[1] / 2;              // 800000
  const int* srcp = ei;
  const int* dstp = ei + E;

  char* ws = (char*)d_ws;
  size_t off = 0;
  auto alloc = [&](size_t sz) -> char* {
    char* p = ws + off;
    off += sz;
    off = (off + 255) & ~(size_t)255;
    return p;
  };

  bf16_t* xb    = (bf16_t*)alloc((size_t)NPAD2 * 512 * 2);
  bf16_t* hb    = (bf16_t*)alloc((size_t)NPAD2 * 512 * 2);
  bf16_t* meanb = (bf16_t*)alloc((size_t)NPAD2 * 512 * 2);
  bf16_t* WB1   = (bf16_t*)alloc((size_t)512 * 1024 * 2);
  bf16_t* WB2   = (bf16_t*)alloc((size_t)512 * 1024 * 2);
  int* deg      = (int*)alloc((size_t)N * 4);
  int* rowS     = (int*)alloc((size_t)(N + 8) * 4);
  int* cursor   = (int*)alloc((size_t)N * 4);
  int* partial  = (int*)alloc(4096);
  int* colb     = (int*)alloc((size_t)E * 4);
  (void)ws_size; (void)n_in; (void)out_size;

  hipMemsetAsync(deg, 0, (size_t)N * 4, stream);

  {
    int total = NPAD2 * 512, valid = N * 512;
    cvt_x_k<<<dim3((total / 8 + 255) / 256), dim3(256), 0, stream>>>(x, xb, total, valid);
  }
  cvt_w_k<<<dim3(256), dim3(256), 0, stream>>>(Wl1, Wr1, WB1);
  cvt_w_k<<<dim3(256), dim3(256), 0, stream>>>(Wl2, Wr2, WB2);

  deg_k<<<dim3((E + 255) / 256), dim3(256), 0, stream>>>(dstp, deg, E);

  int NB = (N + 511) / 512;  // 98
  scan_part_k<<<dim3(NB), dim3(512), 0, stream>>>(deg, partial, N);
  scan_off_k<<<dim3(1), dim3(128), 0, stream>>>(partial, NB, rowS, N);
  scan_blk_k<<<dim3(NB), dim3(512), 0, stream>>>(deg, partial, rowS, cursor, N);
  scat_k<<<dim3((E + 255) / 256), dim3(256), 0, stream>>>(srcp, dstp, cursor, colb, E);

  // layer 1
  agg_k<<<dim3(NPAD2 / 4), dim3(256), 0, stream>>>(xb, rowS, colb, meanb, N, NPAD2);
  dim3 grid(GEMM_BLOCKS);
  gemm_k<true, bf16_t><<<grid, dim3(512), 0, stream>>>(meanb, xb, WB1, b1, hb, NPAD2);

  // layer 2
  agg_k<<<dim3(NPAD2 / 4), dim3(256), 0, stream>>>(hb, rowS, colb, meanb, N, NPAD2);
  gemm_k<false, float><<<grid, dim3(512), 0, stream>>>(meanb, hb, WB2, b2, (float*)d_out, N);
}

// Round 6
// 532.029 us; speedup vs baseline: 1.0702x; 1.0320x over previous
//
#include <hip/hip_runtime.h>

typedef __bf16 bf16_t;
typedef __bf16 bf16x8 __attribute__((ext_vector_type(8)));
typedef float  f32x4  __attribute__((ext_vector_type(4)));

#define D_FEAT 512
#define M_TILES 392            // 392*128 = 50176 rows (padded)
#define NPAD2 (M_TILES * 128)
#define N_TILES 4              // 512 / 128
#define GEMM_BLOCKS (M_TILES * N_TILES)  // 1568 = 8*196

// ---------------- convert x (f32) -> padded bf16 ----------------
__global__ void cvt_x_k(const float* __restrict__ x, bf16_t* __restrict__ xb,
                        int total, int valid) {
  int idx = (blockIdx.x * 256 + threadIdx.x) * 8;
  if (idx >= total) return;
  bf16x8 o;
  if (idx < valid) {
    const float4* p = (const float4*)(x + idx);
    float4 a = p[0], b = p[1];
    o[0] = (bf16_t)a.x; o[1] = (bf16_t)a.y; o[2] = (bf16_t)a.z; o[3] = (bf16_t)a.w;
    o[4] = (bf16_t)b.x; o[5] = (bf16_t)b.y; o[6] = (bf16_t)b.z; o[7] = (bf16_t)b.w;
  } else {
#pragma unroll
    for (int i = 0; i < 8; ++i) o[i] = (bf16_t)0.f;
  }
  *(bf16x8*)(xb + idx) = o;
}

// ------------- build combined weights WB[n][k] (bf16, [512][1024]), both layers -------------
__global__ void cvt_w_k(const float* __restrict__ Wl1, const float* __restrict__ Wr1,
                        bf16_t* __restrict__ WB1,
                        const float* __restrict__ Wl2, const float* __restrict__ Wr2,
                        bf16_t* __restrict__ WB2) {
  int b = blockIdx.x;
  const float* Wl = (b < 256) ? Wl1 : Wl2;
  const float* Wr = (b < 256) ? Wr1 : Wr2;
  bf16_t* WB = (b < 256) ? WB1 : WB2;
  int idx = ((b & 255) * 256 + threadIdx.x) * 8;  // into [512][1024]
  int n = idx >> 10, k = idx & 1023;
  const float* s = (k < 512) ? (Wl + n * 512 + k) : (Wr + n * 512 + k - 512);
  const float4* p = (const float4*)s;
  float4 a = p[0], c = p[1];
  bf16x8 o;
  o[0] = (bf16_t)a.x; o[1] = (bf16_t)a.y; o[2] = (bf16_t)a.z; o[3] = (bf16_t)a.w;
  o[4] = (bf16_t)c.x; o[5] = (bf16_t)c.y; o[6] = (bf16_t)c.z; o[7] = (bf16_t)c.w;
  *(bf16x8*)(WB + idx) = o;
}

// ---------------- CSR build ----------------
__global__ void deg_k(const int* __restrict__ dst, int* __restrict__ deg, int E) {
  int e = blockIdx.x * 256 + threadIdx.x;
  if (e < E) atomicAdd(&deg[dst[e]], 1);
}

__global__ void scan_part_k(const int* __restrict__ deg, int* __restrict__ partial, int N) {
  __shared__ int sd[512];
  int tid = threadIdx.x;
  int i = blockIdx.x * 512 + tid;
  sd[tid] = (i < N) ? deg[i] : 0;
  __syncthreads();
  for (int s = 256; s > 0; s >>= 1) {
    if (tid < s) sd[tid] += sd[tid + s];
    __syncthreads();
  }
  if (tid == 0) partial[blockIdx.x] = sd[0];
}

// parallel one-block exclusive scan over nb (<=128) block partials
__global__ void scan_off_k(int* __restrict__ partial, int nb, int* __restrict__ rowS, int N) {
  __shared__ int sd[128];
  int tid = threadIdx.x;  // 128 threads
  int v = (tid < nb) ? partial[tid] : 0;
  sd[tid] = v;
  __syncthreads();
#pragma unroll
  for (int offd = 1; offd < 128; offd <<= 1) {
    int t = (tid >= offd) ? sd[tid - offd] : 0;
    __syncthreads();
    sd[tid] += t;
    __syncthreads();
  }
  if (tid < nb) partial[tid] = sd[tid] - v;  // exclusive
  if (tid == nb - 1) rowS[N] = sd[tid];      // total
}

__global__ void scan_blk_k(const int* __restrict__ deg, const int* __restrict__ partial,
                           int* __restrict__ rowS, int* __restrict__ cursor, int N) {
  __shared__ int sd[512];
  int tid = threadIdx.x;
  int i = blockIdx.x * 512 + tid;
  int v = (i < N) ? deg[i] : 0;
  sd[tid] = v;
  __syncthreads();
  for (int offd = 1; offd < 512; offd <<= 1) {
    int t = (tid >= offd) ? sd[tid - offd] : 0;
    __syncthreads();
    sd[tid] += t;
    __syncthreads();
  }
  int excl = sd[tid] - v + partial[blockIdx.x];
  if (i < N) { rowS[i] = excl; cursor[i] = excl; }
}

__global__ void scat_k(const int* __restrict__ src, const int* __restrict__ dst,
                       int* __restrict__ cursor, int* __restrict__ col, int E) {
  int e = blockIdx.x * 256 + threadIdx.x;
  if (e < E) {
    int d = dst[e];
    int p = atomicAdd(&cursor[d], 1);
    col[p] = src[e];
  }
}

// ---------------- mean aggregation: out[i] = mean_{j in N(i)} X[col[j]] ----------------
// Split by node-range across 2 dispatches (visibility + more concurrent waves).
__global__ __launch_bounds__(256) void agg_k(const bf16_t* __restrict__ X,
                                             const int* __restrict__ rs,
                                             const int* __restrict__ col,
                                             bf16_t* __restrict__ out,
                                             int N, int nbase) {
  const int lane = threadIdx.x & 63;
  const int node = nbase + blockIdx.x * 4 + (threadIdx.x >> 6);
  const size_t obase = (size_t)node * D_FEAT + lane * 8;
  bf16x8 o;
  if (node >= N) {
#pragma unroll
    for (int i = 0; i < 8; ++i) o[i] = (bf16_t)0.f;
    *(bf16x8*)(out + obase) = o;
    return;
  }
  const int s = rs[node], e = rs[node + 1];
  const int loff = lane * 8;
  float acc[8] = {0.f, 0.f, 0.f, 0.f, 0.f, 0.f, 0.f, 0.f};
  int j = s;
  for (; j + 8 <= e; j += 8) {
    int c0 = col[j + 0], c1 = col[j + 1], c2 = col[j + 2], c3 = col[j + 3];
    int c4 = col[j + 4], c5 = col[j + 5], c6 = col[j + 6], c7 = col[j + 7];
    bf16x8 v0 = *(const bf16x8*)(X + (size_t)c0 * D_FEAT + loff);
    bf16x8 v1 = *(const bf16x8*)(X + (size_t)c1 * D_FEAT + loff);
    bf16x8 v2 = *(const bf16x8*)(X + (size_t)c2 * D_FEAT + loff);
    bf16x8 v3 = *(const bf16x8*)(X + (size_t)c3 * D_FEAT + loff);
    bf16x8 v4 = *(const bf16x8*)(X + (size_t)c4 * D_FEAT + loff);
    bf16x8 v5 = *(const bf16x8*)(X + (size_t)c5 * D_FEAT + loff);
    bf16x8 v6 = *(const bf16x8*)(X + (size_t)c6 * D_FEAT + loff);
    bf16x8 v7 = *(const bf16x8*)(X + (size_t)c7 * D_FEAT + loff);
#pragma unroll
    for (int i = 0; i < 8; ++i) {
      float s01 = (float)v0[i] + (float)v1[i];
      float s23 = (float)v2[i] + (float)v3[i];
      float s45 = (float)v4[i] + (float)v5[i];
      float s67 = (float)v6[i] + (float)v7[i];
      acc[i] += (s01 + s23) + (s45 + s67);
    }
  }
  for (; j + 2 <= e; j += 2) {
    int c0 = col[j + 0], c1 = col[j + 1];
    bf16x8 v0 = *(const bf16x8*)(X + (size_t)c0 * D_FEAT + loff);
    bf16x8 v1 = *(const bf16x8*)(X + (size_t)c1 * D_FEAT + loff);
#pragma unroll
    for (int i = 0; i < 8; ++i) acc[i] += (float)v0[i] + (float)v1[i];
  }
  for (; j < e; ++j) {
    int c0 = col[j];
    bf16x8 v0 = *(const bf16x8*)(X + (size_t)c0 * D_FEAT + loff);
#pragma unroll
    for (int i = 0; i < 8; ++i) acc[i] += (float)v0[i];
  }
  float sc = (e > s) ? 1.0f / (float)(e - s) : 0.f;
#pragma unroll
  for (int i = 0; i < 8; ++i) o[i] = (bf16_t)(acc[i] * sc);
  *(bf16x8*)(out + obase) = o;
}

// ---------------- fused GEMM: out[m][n] = sum_k [A0|A1][m][k] * WB[n][k] + bias[n] ----------------
// 128x128 tile, BK=64, 4 waves (2x2, per-wave 64x64), 2-phase double-buffered
// LDS (64 KB -> 2 blocks/CU), global_load_lds w/ source-side XOR swizzle.
// LDS[row][s] holds global k-chunk (s ^ (row&7)); involution on the global
// source at stage time and on the ds_read slot -> 2-way banked reads (free).
__device__ __forceinline__ void gload_lds16(const void* g, void* l) {
  __builtin_amdgcn_global_load_lds(
      (const __attribute__((address_space(1))) unsigned int*)g,
      (__attribute__((address_space(3))) unsigned int*)l,
      16, 0, 0);
}

template <bool RELU, typename OT>
__global__ __launch_bounds__(256, 2) void gemm_k(
    const bf16_t* __restrict__ A0,   // K 0..511   (mean features), NPAD2 rows
    const bf16_t* __restrict__ A1,   // K 512..1023 (self features), NPAD2 rows
    const bf16_t* __restrict__ WB,   // [512][1024]
    const float* __restrict__ bias,  // [512]
    OT* __restrict__ out, int M) {
  // XCD-chunked bijective remap: 1568 blocks = 8 XCDs x 196; the 4 n-tiles of
  // one m-tile stay consecutive on one XCD -> A tile L2-hits after first block.
  const int t = (blockIdx.x & 7) * (GEMM_BLOCKS / 8) + (blockIdx.x >> 3);
  const int mt = t >> 2;
  const int nt = t & 3;

  // per buf: A 128x64 (8192 us) + B 128x64 (8192 us) = 32 KB; x2 = 64 KB
  __shared__ __align__(16) unsigned short smem[2 * 16384];

  const int tid = threadIdx.x;
  const int lane = tid & 63;
  const int wave = tid >> 6;
  const int wr = wave >> 1;            // 0..1
  const int wc = wave & 1;             // 0..1
  const int m0 = mt * 128;
  const int n0 = nt * 128;

  f32x4 acc[4][4];
#pragma unroll
  for (int m = 0; m < 4; ++m)
#pragma unroll
    for (int n = 0; n < 4; ++n) acc[m][n] = (f32x4){0.f, 0.f, 0.f, 0.f};

  // ---- staging geometry (lane-constant, hoisted) ----
  const int srow = tid >> 3;           // 0..31
  const int sslot = tid & 7;           // 0..7 (16B slots per 128B k-row)
  const int kc = sslot ^ (srow & 7);   // global k-chunk this lane fetches
  const int ldsOff = srow * 64 + sslot * 8;  // ushort idx; +l*2048 per 32-row segment
  size_t gA[4], gB[4];
#pragma unroll
  for (int l = 0; l < 4; ++l) {
    gA[l] = (size_t)(m0 + l * 32 + srow) * 1024 + kc * 16;  // A row stride 1024B
    gB[l] = (size_t)(n0 + l * 32 + srow) * 2048 + kc * 16;  // WB row stride 2048B
  }

  auto stage = [&](int buf, int kk) {
    unsigned short* sA = smem + buf * 16384;
    unsigned short* sB = sA + 8192;
    const int k0 = kk * 64;
    const char* Ab = (k0 < 512) ? (const char*)A0 : (const char*)A1;
    const size_t ka = (size_t)(k0 & 511) * 2;
    const size_t kb = (size_t)k0 * 2;
#pragma unroll
    for (int l = 0; l < 4; ++l) {
      gload_lds16(Ab + gA[l] + ka, sA + ldsOff + l * 2048);
      gload_lds16((const char*)WB + gB[l] + kb, sB + ldsOff + l * 2048);
    }
  };

  // ---- fragment-read offsets (ushort indices), ks = k-slice (0/1) ----
  const int fr = lane & 15;
  const int g = lane >> 4;
  int rdA[2][4], rdB[2][4];
#pragma unroll
  for (int ks = 0; ks < 2; ++ks) {
    const int sl = ((ks * 4 + g) ^ (fr & 7)) * 8;
#pragma unroll
    for (int m = 0; m < 4; ++m) rdA[ks][m] = (wr * 64 + m * 16 + fr) * 64 + sl;
#pragma unroll
    for (int n = 0; n < 4; ++n) rdB[ks][n] = (wc * 64 + n * 16 + fr) * 64 + sl;
  }

  stage(0, 0);
  int cur = 0;
  const int NK = 16;  // K=1024 / BK=64
  for (int kk = 0; kk < NK; ++kk) {
    __syncthreads();  // drains vmcnt: buf[cur] staged; buf[cur^1] free
    if (kk + 1 < NK) stage(cur ^ 1, kk + 1);
    unsigned short* sA = smem + cur * 16384;
    unsigned short* sB = sA + 8192;
#pragma unroll
    for (int ks = 0; ks < 2; ++ks) {
      bf16x8 aF[4], bF[4];
#pragma unroll
      for (int m = 0; m < 4; ++m) aF[m] = *(const bf16x8*)(sA + rdA[ks][m]);
#pragma unroll
      for (int n = 0; n < 4; ++n) bF[n] = *(const bf16x8*)(sB + rdB[ks][n]);
#pragma unroll
      for (int m = 0; m < 4; ++m)
#pragma unroll
        for (int n = 0; n < 4; ++n)
          acc[m][n] = __builtin_amdgcn_mfma_f32_16x16x32_bf16(aF[m], bF[n], acc[m][n], 0, 0, 0);
    }
    cur ^= 1;
  }

  // epilogue: C/D layout col=lane&15, row=(lane>>4)*4+r
#pragma unroll
  for (int n = 0; n < 4; ++n) {
    int coln = n0 + wc * 64 + n * 16 + fr;
    float bv = bias[coln];
#pragma unroll
    for (int m = 0; m < 4; ++m) {
      int rbase = m0 + wr * 64 + m * 16 + g * 4;
#pragma unroll
      for (int r = 0; r < 4; ++r) {
        int row = rbase + r;
        if (row < M) {
          float v = acc[m][n][r] + bv;
          if (RELU) v = fmaxf(v, 0.f);
          out[(size_t)row * 512 + coln] = (OT)v;
        }
      }
    }
  }
}

extern "C" void kernel_launch(void* const* d_in, const int* in_sizes, int n_in,
                              void* d_out, int out_size, void* d_ws, size_t ws_size,
                              hipStream_t stream) {
  const float* x   = (const float*)d_in[0];
  const int*   ei  = (const int*)d_in[1];
  const float* Wl1 = (const float*)d_in[2];
  const float* Wr1 = (const float*)d_in[3];
  const float* b1  = (const float*)d_in[4];
  const float* Wl2 = (const float*)d_in[5];
  const float* Wr2 = (const float*)d_in[6];
  const float* b2  = (const float*)d_in[7];

  const int N = in_sizes[0] / 512;            // 50000
  const int E = in_sizes[1] / 2;              // 800000
  const int* srcp = ei;
  const int* dstp = ei + E;

  char* ws = (char*)d_ws;
  size_t off = 0;
  auto alloc = [&](size_t sz) -> char* {
    char* p = ws + off;
    off += sz;
    off = (off + 255) & ~(size_t)255;
    return p;
  };

  bf16_t* xb    = (bf16_t*)alloc((size_t)NPAD2 * 512 * 2);
  bf16_t* hb    = (bf16_t*)alloc((size_t)NPAD2 * 512 * 2);
  bf16_t* meanb = (bf16_t*)alloc((size_t)NPAD2 * 512 * 2);
  bf16_t* WB1   = (bf16_t*)alloc((size_t)512 * 1024 * 2);
  bf16_t* WB2   = (bf16_t*)alloc((size_t)512 * 1024 * 2);
  int* deg      = (int*)alloc((size_t)N * 4);
  int* rowS     = (int*)alloc((size_t)(N + 8) * 4);
  int* cursor   = (int*)alloc((size_t)N * 4);
  int* partial  = (int*)alloc(4096);
  int* colb     = (int*)alloc((size_t)E * 4);
  (void)ws_size; (void)n_in; (void)out_size;

  hipMemsetAsync(deg, 0, (size_t)N * 4, stream);

  {
    int total = NPAD2 * 512, valid = N * 512;
    cvt_x_k<<<dim3((total / 8 + 255) / 256), dim3(256), 0, stream>>>(x, xb, total, valid);
  }
  cvt_w_k<<<dim3(512), dim3(256), 0, stream>>>(Wl1, Wr1, WB1, Wl2, Wr2, WB2);

  deg_k<<<dim3((E + 255) / 256), dim3(256), 0, stream>>>(dstp, deg, E);

  int NB = (N + 511) / 512;  // 98
  scan_part_k<<<dim3(NB), dim3(512), 0, stream>>>(deg, partial, N);
  scan_off_k<<<dim3(1), dim3(128), 0, stream>>>(partial, NB, rowS, N);
  scan_blk_k<<<dim3(NB), dim3(512), 0, stream>>>(deg, partial, rowS, cursor, N);
  scat_k<<<dim3((E + 255) / 256), dim3(256), 0, stream>>>(srcp, dstp, cursor, colb, E);

  const int HALF = NPAD2 / 2;  // 25088
  dim3 agrid(HALF / 4);
  dim3 grid(GEMM_BLOCKS);

  // layer 1
  agg_k<<<agrid, dim3(256), 0, stream>>>(xb, rowS, colb, meanb, N, 0);
  agg_k<<<agrid, dim3(256), 0, stream>>>(xb, rowS, colb, meanb, N, HALF);
  gemm_k<true, bf16_t><<<grid, dim3(256), 0, stream>>>(meanb, xb, WB1, b1, hb, NPAD2);

  // layer 2
  agg_k<<<agrid, dim3(256), 0, stream>>>(hb, rowS, colb, meanb, N, 0);
  agg_k<<<agrid, dim3(256), 0, stream>>>(hb, rowS, colb, meanb, N, HALF);
  gemm_k<false, float><<<grid, dim3(256), 0, stream>>>(meanb, hb, WB2, b2, (float*)d_out, N);
}

// Round 7
// 523.584 us; speedup vs baseline: 1.0875x; 1.0161x over previous
//
#include <hip/hip_runtime.h>

typedef __bf16 bf16_t;
typedef __bf16 bf16x8 __attribute__((ext_vector_type(8)));
typedef float  f32x4  __attribute__((ext_vector_type(4)));

#define D_FEAT 512
#define M_TILES 392            // 392*128 = 50176 rows (padded)
#define NPAD2 (M_TILES * 128)
#define N_TILES 4              // 512 / 128
#define GEMM_BLOCKS (M_TILES * N_TILES)  // 1568 = 8*196

// ---------------- convert x (f32) -> padded bf16 ----------------
__global__ void cvt_x_k(const float* __restrict__ x, bf16_t* __restrict__ xb,
                        int total, int valid) {
  int idx = (blockIdx.x * 256 + threadIdx.x) * 8;
  if (idx >= total) return;
  bf16x8 o;
  if (idx < valid) {
    const float4* p = (const float4*)(x + idx);
    float4 a = p[0], b = p[1];
    o[0] = (bf16_t)a.x; o[1] = (bf16_t)a.y; o[2] = (bf16_t)a.z; o[3] = (bf16_t)a.w;
    o[4] = (bf16_t)b.x; o[5] = (bf16_t)b.y; o[6] = (bf16_t)b.z; o[7] = (bf16_t)b.w;
  } else {
#pragma unroll
    for (int i = 0; i < 8; ++i) o[i] = (bf16_t)0.f;
  }
  *(bf16x8*)(xb + idx) = o;
}

// ------------- build combined weights WB[n][k] (bf16, [512][1024]), both layers -------------
__global__ void cvt_w_k(const float* __restrict__ Wl1, const float* __restrict__ Wr1,
                        bf16_t* __restrict__ WB1,
                        const float* __restrict__ Wl2, const float* __restrict__ Wr2,
                        bf16_t* __restrict__ WB2) {
  int b = blockIdx.x;
  const float* Wl = (b < 256) ? Wl1 : Wl2;
  const float* Wr = (b < 256) ? Wr1 : Wr2;
  bf16_t* WB = (b < 256) ? WB1 : WB2;
  int idx = ((b & 255) * 256 + threadIdx.x) * 8;  // into [512][1024]
  int n = idx >> 10, k = idx & 1023;
  const float* s = (k < 512) ? (Wl + n * 512 + k) : (Wr + n * 512 + k - 512);
  const float4* p = (const float4*)s;
  float4 a = p[0], c = p[1];
  bf16x8 o;
  o[0] = (bf16_t)a.x; o[1] = (bf16_t)a.y; o[2] = (bf16_t)a.z; o[3] = (bf16_t)a.w;
  o[4] = (bf16_t)c.x; o[5] = (bf16_t)c.y; o[6] = (bf16_t)c.z; o[7] = (bf16_t)c.w;
  *(bf16x8*)(WB + idx) = o;
}

// ---------------- CSR build ----------------
__global__ void deg_k(const int* __restrict__ dst, int* __restrict__ deg, int E) {
  int e = blockIdx.x * 256 + threadIdx.x;
  if (e < E) atomicAdd(&deg[dst[e]], 1);
}

__global__ void scan_part_k(const int* __restrict__ deg, int* __restrict__ partial, int N) {
  __shared__ int sd[512];
  int tid = threadIdx.x;
  int i = blockIdx.x * 512 + tid;
  sd[tid] = (i < N) ? deg[i] : 0;
  __syncthreads();
  for (int s = 256; s > 0; s >>= 1) {
    if (tid < s) sd[tid] += sd[tid + s];
    __syncthreads();
  }
  if (tid == 0) partial[blockIdx.x] = sd[0];
}

// parallel one-block exclusive scan over nb (<=128) block partials
__global__ void scan_off_k(int* __restrict__ partial, int nb, int* __restrict__ rowS, int N) {
  __shared__ int sd[128];
  int tid = threadIdx.x;  // 128 threads
  int v = (tid < nb) ? partial[tid] : 0;
  sd[tid] = v;
  __syncthreads();
#pragma unroll
  for (int offd = 1; offd < 128; offd <<= 1) {
    int t = (tid >= offd) ? sd[tid - offd] : 0;
    __syncthreads();
    sd[tid] += t;
    __syncthreads();
  }
  if (tid < nb) partial[tid] = sd[tid] - v;  // exclusive
  if (tid == nb - 1) rowS[N] = sd[tid];      // total
}

__global__ void scan_blk_k(const int* __restrict__ deg, const int* __restrict__ partial,
                           int* __restrict__ rowS, int* __restrict__ cursor, int N) {
  __shared__ int sd[512];
  int tid = threadIdx.x;
  int i = blockIdx.x * 512 + tid;
  int v = (i < N) ? deg[i] : 0;
  sd[tid] = v;
  __syncthreads();
  for (int offd = 1; offd < 512; offd <<= 1) {
    int t = (tid >= offd) ? sd[tid - offd] : 0;
    __syncthreads();
    sd[tid] += t;
    __syncthreads();
  }
  int excl = sd[tid] - v + partial[blockIdx.x];
  if (i < N) { rowS[i] = excl; cursor[i] = excl; }
}

__global__ void scat_k(const int* __restrict__ src, const int* __restrict__ dst,
                       int* __restrict__ cursor, int* __restrict__ col, int E) {
  int e = blockIdx.x * 256 + threadIdx.x;
  if (e < E) {
    int d = dst[e];
    int p = atomicAdd(&cursor[d], 1);
    col[p] = src[e];
  }
}

// ---------------- mean aggregation: out[i] = mean_{j in N(i)} X[col[j]] ----------------
__global__ __launch_bounds__(256) void agg_k(const bf16_t* __restrict__ X,
                                             const int* __restrict__ rs,
                                             const int* __restrict__ col,
                                             bf16_t* __restrict__ out,
                                             int N, int nbase) {
  const int lane = threadIdx.x & 63;
  const int node = nbase + blockIdx.x * 4 + (threadIdx.x >> 6);
  const size_t obase = (size_t)node * D_FEAT + lane * 8;
  bf16x8 o;
  if (node >= N) {
#pragma unroll
    for (int i = 0; i < 8; ++i) o[i] = (bf16_t)0.f;
    *(bf16x8*)(out + obase) = o;
    return;
  }
  const int s = rs[node], e = rs[node + 1];
  const int loff = lane * 8;
  float acc[8] = {0.f, 0.f, 0.f, 0.f, 0.f, 0.f, 0.f, 0.f};
  int j = s;
  for (; j + 8 <= e; j += 8) {
    int c0 = col[j + 0], c1 = col[j + 1], c2 = col[j + 2], c3 = col[j + 3];
    int c4 = col[j + 4], c5 = col[j + 5], c6 = col[j + 6], c7 = col[j + 7];
    bf16x8 v0 = *(const bf16x8*)(X + (size_t)c0 * D_FEAT + loff);
    bf16x8 v1 = *(const bf16x8*)(X + (size_t)c1 * D_FEAT + loff);
    bf16x8 v2 = *(const bf16x8*)(X + (size_t)c2 * D_FEAT + loff);
    bf16x8 v3 = *(const bf16x8*)(X + (size_t)c3 * D_FEAT + loff);
    bf16x8 v4 = *(const bf16x8*)(X + (size_t)c4 * D_FEAT + loff);
    bf16x8 v5 = *(const bf16x8*)(X + (size_t)c5 * D_FEAT + loff);
    bf16x8 v6 = *(const bf16x8*)(X + (size_t)c6 * D_FEAT + loff);
    bf16x8 v7 = *(const bf16x8*)(X + (size_t)c7 * D_FEAT + loff);
#pragma unroll
    for (int i = 0; i < 8; ++i) {
      float s01 = (float)v0[i] + (float)v1[i];
      float s23 = (float)v2[i] + (float)v3[i];
      float s45 = (float)v4[i] + (float)v5[i];
      float s67 = (float)v6[i] + (float)v7[i];
      acc[i] += (s01 + s23) + (s45 + s67);
    }
  }
  for (; j + 2 <= e; j += 2) {
    int c0 = col[j + 0], c1 = col[j + 1];
    bf16x8 v0 = *(const bf16x8*)(X + (size_t)c0 * D_FEAT + loff);
    bf16x8 v1 = *(const bf16x8*)(X + (size_t)c1 * D_FEAT + loff);
#pragma unroll
    for (int i = 0; i < 8; ++i) acc[i] += (float)v0[i] + (float)v1[i];
  }
  for (; j < e; ++j) {
    int c0 = col[j];
    bf16x8 v0 = *(const bf16x8*)(X + (size_t)c0 * D_FEAT + loff);
#pragma unroll
    for (int i = 0; i < 8; ++i) acc[i] += (float)v0[i];
  }
  float sc = (e > s) ? 1.0f / (float)(e - s) : 0.f;
#pragma unroll
  for (int i = 0; i < 8; ++i) o[i] = (bf16_t)(acc[i] * sc);
  *(bf16x8*)(out + obase) = o;
}

// ---------------- fused GEMM: out[m][n] = sum_k [A0|A1][m][k] * WB[n][k] + bias[n] ----------------
// 128x128 tile, BK=64, 4 waves, double-buffered LDS (64 KB, 2 blocks/CU).
// T4 counted-vmcnt pipeline: next tile's 8 staging loads stay IN FLIGHT across
// the barriers (s_waitcnt vmcnt(8), never 0 in-loop); raw s_barrier (no drain).
// Source-side XOR swizzle unchanged from the R6 passing kernel.
__device__ __forceinline__ void gload_lds16(const void* g, void* l) {
  __builtin_amdgcn_global_load_lds(
      (const __attribute__((address_space(1))) unsigned int*)g,
      (__attribute__((address_space(3))) unsigned int*)l,
      16, 0, 0);
}

template <bool RELU, typename OT>
__global__ __launch_bounds__(256, 2) void gemm_k(
    const bf16_t* __restrict__ A0,   // K 0..511   (mean features), NPAD2 rows
    const bf16_t* __restrict__ A1,   // K 512..1023 (self features), NPAD2 rows
    const bf16_t* __restrict__ WB,   // [512][1024]
    const float* __restrict__ bias,  // [512]
    OT* __restrict__ out, int M) {
  // XCD-chunked bijective remap: 1568 blocks = 8 XCDs x 196.
  const int t = (blockIdx.x & 7) * (GEMM_BLOCKS / 8) + (blockIdx.x >> 3);
  const int mt = t >> 2;
  const int nt = t & 3;

  __shared__ __align__(16) unsigned short smem[2 * 16384];

  const int tid = threadIdx.x;
  const int lane = tid & 63;
  const int wave = tid >> 6;
  const int wr = wave >> 1;            // 0..1
  const int wc = wave & 1;             // 0..1
  const int m0 = mt * 128;
  const int n0 = nt * 128;

  f32x4 acc[4][4];
#pragma unroll
  for (int m = 0; m < 4; ++m)
#pragma unroll
    for (int n = 0; n < 4; ++n) acc[m][n] = (f32x4){0.f, 0.f, 0.f, 0.f};

  // ---- staging geometry (lane-constant, hoisted) ----
  const int srow = tid >> 3;           // 0..31
  const int sslot = tid & 7;           // 0..7 (16B slots per 128B k-row)
  const int kc = sslot ^ (srow & 7);   // global k-chunk this lane fetches
  const int ldsOff = srow * 64 + sslot * 8;  // ushort idx; +l*2048 per 32-row segment
  size_t gA[4], gB[4];
#pragma unroll
  for (int l = 0; l < 4; ++l) {
    gA[l] = (size_t)(m0 + l * 32 + srow) * 1024 + kc * 16;  // A row stride 1024B
    gB[l] = (size_t)(n0 + l * 32 + srow) * 2048 + kc * 16;  // WB row stride 2048B
  }

  auto stage = [&](int buf, int kk) {
    unsigned short* sA = smem + buf * 16384;
    unsigned short* sB = sA + 8192;
    const int k0 = kk * 64;
    const char* Ab = (k0 < 512) ? (const char*)A0 : (const char*)A1;
    const size_t ka = (size_t)(k0 & 511) * 2;
    const size_t kb = (size_t)k0 * 2;
#pragma unroll
    for (int l = 0; l < 4; ++l) {
      gload_lds16(Ab + gA[l] + ka, sA + ldsOff + l * 2048);
      gload_lds16((const char*)WB + gB[l] + kb, sB + ldsOff + l * 2048);
    }
  };

  // ---- fragment-read offsets (ushort indices), ks = k-slice (0/1) ----
  const int fr = lane & 15;
  const int g = lane >> 4;
  int rdA[2][4], rdB[2][4];
#pragma unroll
  for (int ks = 0; ks < 2; ++ks) {
    const int sl = ((ks * 4 + g) ^ (fr & 7)) * 8;
#pragma unroll
    for (int m = 0; m < 4; ++m) rdA[ks][m] = (wr * 64 + m * 16 + fr) * 64 + sl;
#pragma unroll
    for (int n = 0; n < 4; ++n) rdB[ks][n] = (wc * 64 + n * 16 + fr) * 64 + sl;
  }

  // ---- prologue: 2 tiles in flight (16 loads/thread outstanding) ----
  stage(0, 0);
  stage(1, 1);
  __builtin_amdgcn_sched_barrier(0);

  const int NK = 16;  // K=1024 / BK=64
  for (int kk = 0; kk < NK; ++kk) {
    const int cur = kk & 1;
    // wait: this tile's 8 loads done; next tile's 8 REMAIN in flight
    if (kk < NK - 1) {
      asm volatile("s_waitcnt vmcnt(8)" ::: "memory");
    } else {
      asm volatile("s_waitcnt vmcnt(0)" ::: "memory");
    }
    __builtin_amdgcn_sched_barrier(0);
    __builtin_amdgcn_s_barrier();      // all waves' tile-kk loads landed
    __builtin_amdgcn_sched_barrier(0);

    unsigned short* sA = smem + cur * 16384;
    unsigned short* sB = sA + 8192;
    __builtin_amdgcn_s_setprio(1);
#pragma unroll
    for (int ks = 0; ks < 2; ++ks) {
      bf16x8 aF[4], bF[4];
#pragma unroll
      for (int m = 0; m < 4; ++m) aF[m] = *(const bf16x8*)(sA + rdA[ks][m]);
#pragma unroll
      for (int n = 0; n < 4; ++n) bF[n] = *(const bf16x8*)(sB + rdB[ks][n]);
#pragma unroll
      for (int m = 0; m < 4; ++m)
#pragma unroll
        for (int n = 0; n < 4; ++n)
          acc[m][n] = __builtin_amdgcn_mfma_f32_16x16x32_bf16(aF[m], bF[n], acc[m][n], 0, 0, 0);
    }
    __builtin_amdgcn_s_setprio(0);

    __builtin_amdgcn_sched_barrier(0);
    __builtin_amdgcn_s_barrier();      // all waves done reading buf[cur]
    __builtin_amdgcn_sched_barrier(0);
    if (kk + 2 < NK) stage(cur, kk + 2);  // refill freed buffer
    __builtin_amdgcn_sched_barrier(0);
  }

  // epilogue: C/D layout col=lane&15, row=(lane>>4)*4+r
#pragma unroll
  for (int n = 0; n < 4; ++n) {
    int coln = n0 + wc * 64 + n * 16 + fr;
    float bv = bias[coln];
#pragma unroll
    for (int m = 0; m < 4; ++m) {
      int rbase = m0 + wr * 64 + m * 16 + g * 4;
#pragma unroll
      for (int r = 0; r < 4; ++r) {
        int row = rbase + r;
        if (row < M) {
          float v = acc[m][n][r] + bv;
          if (RELU) v = fmaxf(v, 0.f);
          out[(size_t)row * 512 + coln] = (OT)v;
        }
      }
    }
  }
}

extern "C" void kernel_launch(void* const* d_in, const int* in_sizes, int n_in,
                              void* d_out, int out_size, void* d_ws, size_t ws_size,
                              hipStream_t stream) {
  const float* x   = (const float*)d_in[0];
  const int*   ei  = (const int*)d_in[1];
  const float* Wl1 = (const float*)d_in[2];
  const float* Wr1 = (const float*)d_in[3];
  const float* b1  = (const float*)d_in[4];
  const float* Wl2 = (const float*)d_in[5];
  const float* Wr2 = (const float*)d_in[6];
  const float* b2  = (const float*)d_in[7];

  const int N = in_sizes[0] / 512;            // 50000
  const int E = in_sizes[1] / 2;              // 800000
  const int* srcp = ei;
  const int* dstp = ei + E;

  char* ws = (char*)d_ws;
  size_t off = 0;
  auto alloc = [&](size_t sz) -> char* {
    char* p = ws + off;
    off += sz;
    off = (off + 255) & ~(size_t)255;
    return p;
  };

  bf16_t* xb    = (bf16_t*)alloc((size_t)NPAD2 * 512 * 2);
  bf16_t* hb    = (bf16_t*)alloc((size_t)NPAD2 * 512 * 2);
  bf16_t* meanb = (bf16_t*)alloc((size_t)NPAD2 * 512 * 2);
  bf16_t* WB1   = (bf16_t*)alloc((size_t)512 * 1024 * 2);
  bf16_t* WB2   = (bf16_t*)alloc((size_t)512 * 1024 * 2);
  int* deg      = (int*)alloc((size_t)N * 4);
  int* rowS     = (int*)alloc((size_t)(N + 8) * 4);
  int* cursor   = (int*)alloc((size_t)N * 4);
  int* partial  = (int*)alloc(4096);
  int* colb     = (int*)alloc((size_t)E * 4);
  (void)ws_size; (void)n_in; (void)out_size;

  hipMemsetAsync(deg, 0, (size_t)N * 4, stream);

  {
    int total = NPAD2 * 512, valid = N * 512;
    cvt_x_k<<<dim3((total / 8 + 255) / 256), dim3(256), 0, stream>>>(x, xb, total, valid);
  }
  cvt_w_k<<<dim3(512), dim3(256), 0, stream>>>(Wl1, Wr1, WB1, Wl2, Wr2, WB2);

  deg_k<<<dim3((E + 255) / 256), dim3(256), 0, stream>>>(dstp, deg, E);

  int NB = (N + 511) / 512;  // 98
  scan_part_k<<<dim3(NB), dim3(512), 0, stream>>>(deg, partial, N);
  scan_off_k<<<dim3(1), dim3(128), 0, stream>>>(partial, NB, rowS, N);
  scan_blk_k<<<dim3(NB), dim3(512), 0, stream>>>(deg, partial, rowS, cursor, N);
  scat_k<<<dim3((E + 255) / 256), dim3(256), 0, stream>>>(srcp, dstp, cursor, colb, E);

  const int HALF = NPAD2 / 2;  // 25088
  dim3 agrid(HALF / 4);
  dim3 grid(GEMM_BLOCKS);

  // layer 1
  agg_k<<<agrid, dim3(256), 0, stream>>>(xb, rowS, colb, meanb, N, 0);
  agg_k<<<agrid, dim3(256), 0, stream>>>(xb, rowS, colb, meanb, N, HALF);
  gemm_k<true, bf16_t><<<grid, dim3(256), 0, stream>>>(meanb, xb, WB1, b1, hb, NPAD2);

  // layer 2
  agg_k<<<agrid, dim3(256), 0, stream>>>(hb, rowS, colb, meanb, N, 0);
  agg_k<<<agrid, dim3(256), 0, stream>>>(hb, rowS, colb, meanb, N, HALF);
  gemm_k<false, float><<<grid, dim3(256), 0, stream>>>(meanb, hb, WB2, b2, (float*)d_out, N);
}